// Round 5
// baseline (1490.967 us; speedup 1.0000x reference)
//
#include <hip/hip_runtime.h>
#include <hip/hip_bf16.h>

// VectorQuantizer2 forward (VAR multi-scale VQ) on MI355X.
// B=512, C=32, H=64, W=1, V=4096 codes, scales pn=1,2,4,8,16,32,64.
// Identities: f_hat + f_rest == f  ->  loss_si = 1.25*mean(f_rest^2), out = f - f_rest_final.
// Conv 3x3 with W=1 + zero pad == 3x1 conv along H with kernel column kw=1.
// phi index per stage (exact fp64 replay of np.linspace ticks): si=0..6 -> pi=0,0,1,2,2,3,3.
// Argmin exactness: fp32 top-3 (values+indices) per chunk; fp64 re-score of the 3 candidates
// picks the exact chunk winner (index-only partial); finalize re-scores all VS chunk winners
// in fp64 with the SAME dot64 code path -> exact global argmin, first-index ties.

#define B_ 512
#define C_ 32
#define H_ 64
#define V_ 4096
#define TOT (B_*C_*H_)   // 1048576

__device__ __forceinline__ float cubicw(float d) {
    d = fabsf(d);
    const float d2 = d * d, d3 = d2 * d;
    if (d <= 1.0f) return 1.25f * d3 - 2.25f * d2 + 1.0f;          // a=-0.75
    if (d < 2.0f)  return -0.75f * d3 + 3.75f * d2 - 6.0f * d + 3.0f;
    return 0.0f;
}

// fp64 dot of a row (8 float4 in regs) with a code row (global, 128B aligned).
// Same accumulation order everywhere -> bit-identical scores in search and finalize.
__device__ __forceinline__ double dot64v(const float4* a, const float4* ef) {
    double s = 0.0;
#pragma unroll
    for (int k = 0; k < 8; ++k) {
        const float4 e = ef[k];
        s += (double)a[k].x * (double)e.x;
        s += (double)a[k].y * (double)e.y;
        s += (double)a[k].z * (double)e.z;
        s += (double)a[k].w * (double)e.w;
    }
    return s;
}

// ---------------- init: e_sq (f32+f64), compact conv weights, stage-0 pooled rest, zero loss
__global__ __launch_bounds__(256) void vq_init(
    const float* __restrict__ f, const float* __restrict__ emb,
    const float* __restrict__ phi_w,
    float* __restrict__ esqf, double* __restrict__ esqd,
    float* __restrict__ wmidc, float* __restrict__ rest0, float* __restrict__ loss_acc)
{
    const int blk = blockIdx.x, t = threadIdx.x;
    if (blk < 16) {                       // e_sq[4096] in fp64 (exact ordering source)
        const int v = blk * 256 + t;
        const float* er = emb + (long)v * 32;
        double s = 0.0;
#pragma unroll
        for (int k = 0; k < 32; ++k) { const double e = (double)er[k]; s += e * e; }
        esqd[v] = s;
        esqf[v] = (float)s;
    } else if (blk < 20) {                // wmidc[pi][c][cp][kh] = phi_w[pi][c][cp][kh][1]
        const int pi = blk - 16;
        for (int e = t; e < 3072; e += 256) {
            const int c = e / 96, r = e % 96, cp = r / 3, kh = r % 3;
            wmidc[pi * 3072 + e] = phi_w[(long)((pi*32 + c)*32 + cp)*9 + kh*3 + 1];
        }
    } else if (blk < 84) {                // rest0[b][c] = mean_i f[b][c][i]
        const int out = (blk - 20) * 256 + t;
        const int b = out >> 5, c = out & 31;
        const float4* fv = reinterpret_cast<const float4*>(f) + (long)(b*32 + c) * 16;
        float s0=0.f,s1=0.f,s2=0.f,s3=0.f;
#pragma unroll
        for (int k = 0; k < 16; ++k) {
            float4 e = fv[k];
            if ((k&3)==0){s0=s0+e.x+e.y+e.z+e.w;}
            else if((k&3)==1){s1=s1+e.x+e.y+e.z+e.w;}
            else if((k&3)==2){s2=s2+e.x+e.y+e.z+e.w;}
            else {s3=s3+e.x+e.y+e.z+e.w;}
        }
        rest0[out] = ((s0 + s1) + (s2 + s3)) * (1.0f / 64.0f);
    } else {
        if (t == 0) *loss_acc = 0.0f;
    }
}

// ---------------- VQ nearest-code search. 512 rows/block (2/thread), codes split VSPLIT ways.
// fp32 top-3 scan (double-buffered scalar code loads) + fp64 resolve of the 3 candidates.
template<int PN, int VSPLIT>
__global__ __launch_bounds__(256, 4) void vq_search(
    const float* __restrict__ rest,   // [B*PN][32]
    const float* __restrict__ emb,    // [4096][32]
    const float* __restrict__ esqf,   // [4096]
    const double* __restrict__ esqd,  // [4096]
    int* __restrict__ mini_p)         // [B*PN*VSPLIT] exact chunk-winner index
{
    constexpr int VC = V_ / VSPLIT;   // codes per chunk (even, >=16)
    const int t = threadIdx.x;
    const long rowbase = (long)blockIdx.x * 512;
    const int vs = blockIdx.y;
    const long r0 = rowbase + t, r1 = r0 + 256;
    const float4* __restrict__ rv = reinterpret_cast<const float4*>(rest);
    const float4* __restrict__ ev = reinterpret_cast<const float4*>(emb);

    float4 a[8], b8[8];
#pragma unroll
    for (int k = 0; k < 8; ++k) { a[k] = rv[r0*8 + k]; b8[k] = rv[r1*8 + k]; }

    const int j0 = vs * VC;
    const float INF = 3.402823466e38f;
    float m1a=INF,m2a=INF,m3a=INF, m1b=INF,m2b=INF,m3b=INF;
    int i1a=j0,i2a=j0,i3a=j0, i1b=j0,i2b=j0,i3b=j0;

#define SCORE(EB, ES, J) do {                                                  \
        const int _j = (J);                                                    \
        float pa[4]={0,0,0,0}, pb[4]={0,0,0,0};                                \
        _Pragma("unroll")                                                      \
        for (int k = 0; k < 8; ++k) {                                          \
            const int s_ = k & 3;                                              \
            pa[s_]=fmaf(a[k].x,EB[k].x,pa[s_]); pa[s_]=fmaf(a[k].y,EB[k].y,pa[s_]); \
            pa[s_]=fmaf(a[k].z,EB[k].z,pa[s_]); pa[s_]=fmaf(a[k].w,EB[k].w,pa[s_]); \
            pb[s_]=fmaf(b8[k].x,EB[k].x,pb[s_]); pb[s_]=fmaf(b8[k].y,EB[k].y,pb[s_]); \
            pb[s_]=fmaf(b8[k].z,EB[k].z,pb[s_]); pb[s_]=fmaf(b8[k].w,EB[k].w,pb[s_]); \
        }                                                                      \
        const float sa = fmaf(-2.0f,(pa[0]+pa[1])+(pa[2]+pa[3]),ES);           \
        const float sb = fmaf(-2.0f,(pb[0]+pb[1])+(pb[2]+pb[3]),ES);           \
        { const bool c1=sa<m1a, c2=sa<m2a, c3=sa<m3a;                          \
          m3a = c2?m2a:(c3?sa:m3a); i3a = c2?i2a:(c3?_j:i3a);                  \
          m2a = c1?m1a:(c2?sa:m2a); i2a = c1?i1a:(c2?_j:i2a);                  \
          m1a = c1?sa:m1a;          i1a = c1?_j:i1a; }                         \
        { const bool c1=sb<m1b, c2=sb<m2b, c3=sb<m3b;                          \
          m3b = c2?m2b:(c3?sb:m3b); i3b = c2?i2b:(c3?_j:i3b);                  \
          m2b = c1?m1b:(c2?sb:m2b); i2b = c1?i1b:(c2?_j:i2b);                  \
          m1b = c1?sb:m1b;          i1b = c1?_j:i1b; }                         \
    } while (0)

    float4 e0[8], e1[8]; float es0, es1;
#pragma unroll
    for (int k = 0; k < 8; ++k) e0[k] = ev[(long)j0*8 + k];
    es0 = esqf[j0];

#pragma unroll 1
    for (int jj = 0; jj < VC; jj += 2) {
        const int j1 = j0 + jj + 1;
#pragma unroll
        for (int k = 0; k < 8; ++k) e1[k] = ev[(long)j1*8 + k];
        es1 = esqf[j1];
        SCORE(e0, es0, j0 + jj);
        const int j2 = (jj + 2 < VC) ? (j0 + jj + 2) : j0;   // uniform clamp
#pragma unroll
        for (int k = 0; k < 8; ++k) e0[k] = ev[(long)j2*8 + k];
        es0 = esqf[j2];
        SCORE(e1, es1, j1);
    }
#undef SCORE

    // Exact fp64 resolve among the 3 fp32 candidates (lexicographic (value, index)).
    {
        double bv = 1e300; int bi = 0x7fffffff;
        const int cand[3] = { i1a, i2a, i3a };
#pragma unroll
        for (int c = 0; c < 3; ++c) {
            const int j = cand[c];
            const double v = esqd[j] - 2.0 * dot64v(a, ev + (long)j*8);
            if (v < bv || (v == bv && j < bi)) { bv = v; bi = j; }
        }
        mini_p[r0*VSPLIT + vs] = bi;
    }
    {
        double bv = 1e300; int bi = 0x7fffffff;
        const int cand[3] = { i1b, i2b, i3b };
#pragma unroll
        for (int c = 0; c < 3; ++c) {
            const int j = cand[c];
            const double v = esqd[j] - 2.0 * dot64v(b8, ev + (long)j*8);
            if (v < bv || (v == bv && j < bi)) { bv = v; bi = j; }
        }
        mini_p[r1*VSPLIT + vs] = bi;
    }
}

// ---------------- finalize: exact cross-chunk argmin (fp64 re-score), gather, bicubic up,
//                  3x1 conv, residual + loss + next-stage pooling
template<int PN, int VS, int PI, int NPN, bool FIRST, bool LAST>
__global__ __launch_bounds__(256) void vq_finalize(
    const float* __restrict__ f,
    const float* __restrict__ emb,
    const float* __restrict__ rest_cur,  // [B*PN][32] current stage pooled rows
    const int*   __restrict__ mini_p,    // [B*PN*VS]
    const double* __restrict__ esqd,
    const float* __restrict__ wmidc,     // [4][32][32][3]
    const float* __restrict__ phi_b,     // [4][32]
    float* __restrict__ f_rest,
    float* __restrict__ rest_next,       // [B*NPN][32]
    float* __restrict__ loss_acc,
    float* __restrict__ f_hat_out)
{
    __shared__ int   idx_s[PN];
    __shared__ float hs[32][65];
    __shared__ float huc[32][68];      // rows i+1 for i in [-1,64]; cols 0 and 65 zero pad
    __shared__ float wsum[4];
    const int t = threadIdx.x;
    const int b = blockIdx.x;
    const float4* __restrict__ ev = reinterpret_cast<const float4*>(emb);

    // ---- exact argmin across VS chunk winners: TPR threads per row, fp64 re-score.
    {
        constexpr int TPR = (256/PN < 8) ? (256/PN) : 8;   // 8,8,8,8,8,8,4
        constexpr int EPT = VS / TPR;
        static_assert(VS % TPR == 0, "VS % TPR");
        const int row = t / TPR, k = t % TPR;
        if (row < PN) {
            const float4* rrow = reinterpret_cast<const float4*>(rest_cur) +
                                 ((long)b*PN + row)*8;
            float4 rr[8];
#pragma unroll
            for (int kk = 0; kk < 8; ++kk) rr[kk] = rrow[kk];
            const long pbase = ((long)b*PN + row)*VS;
            double bv = 1e300; int bi = 0x7fffffff;
            for (int e = k*EPT; e < (k+1)*EPT; ++e) {
                const int ii = mini_p[pbase + e];
                const double v = esqd[ii] - 2.0 * dot64v(rr, ev + (long)ii*8);
                if (v < bv || (v == bv && ii < bi)) { bv = v; bi = ii; }
            }
#pragma unroll
            for (int off = TPR>>1; off; off >>= 1) {
                const double ov = __shfl_xor(bv, off);
                const int    oi = __shfl_xor(bi, off);
                if (ov < bv || (ov == bv && oi < bi)) { bv = ov; bi = oi; }
            }
            if (k == 0) idx_s[row] = bi;
        }
    }
    if (t < 32) { huc[t][0] = 0.0f; huc[t][65] = 0.0f; }
    __syncthreads();

    for (int e = t; e < PN*32; e += 256) {   // gather codes: hs[c][p]
        const int c = e & 31, p = e >> 5;
        hs[c][p] = emb[(long)idx_s[p]*32 + c];
    }
    __syncthreads();

    const int i  = t & 63;             // lane = output position along H
    const int wv = t >> 6;             // wave = channel block of 8
    const int c0 = wv * 8;
    if constexpr (PN == 64) {
#pragma unroll
        for (int o = 0; o < 8; ++o) huc[c0+o][i+1] = hs[c0+o][i];
    } else {
        constexpr float scale = (float)PN / 64.0f;
        const float src = ((float)i + 0.5f) * scale - 0.5f;
        const float fi0 = floorf(src);
        const float tt  = src - fi0;
        const int   i0  = (int)fi0;
        const float w0 = cubicw(tt + 1.0f), w1 = cubicw(tt);
        const float w2 = cubicw(1.0f - tt), w3 = cubicw(2.0f - tt);
        const int k0 = min(max(i0 - 1, 0), PN - 1);
        const int k1 = min(max(i0    , 0), PN - 1);
        const int k2 = min(max(i0 + 1, 0), PN - 1);
        const int k3 = min(max(i0 + 2, 0), PN - 1);
#pragma unroll
        for (int o = 0; o < 8; ++o) {
            const int c = c0 + o;
            float v = w0 * hs[c][k0];
            v = fmaf(w1, hs[c][k1], v);
            v = fmaf(w2, hs[c][k2], v);
            v = fmaf(w3, hs[c][k3], v);
            huc[c][i+1] = v;
        }
    }
    __syncthreads();

    // 3x1 conv along H; weights wave-uniform -> scalar loads
    const int c0u = __builtin_amdgcn_readfirstlane(c0);
    const float* __restrict__ wb = wmidc + PI*3072 + c0u*96;
    float acc[8] = {0,0,0,0,0,0,0,0};
#pragma unroll 8
    for (int cp = 0; cp < 32; ++cp) {
        const float x0 = huc[cp][i];
        const float x1 = huc[cp][i+1];
        const float x2 = huc[cp][i+2];
#pragma unroll
        for (int o = 0; o < 8; ++o) {
            const float* w = wb + o*96 + cp*3;
            acc[o] = fmaf(w[0], x0, acc[o]);
            acc[o] = fmaf(w[1], x1, acc[o]);
            acc[o] = fmaf(w[2], x2, acc[o]);
        }
    }

    float sq = 0.0f;
#pragma unroll
    for (int o = 0; o < 8; ++o) {
        const int c = c0 + o;
        const float h  = huc[c][i+1];
        const float hn = 0.5f * h + 0.5f * (acc[o] + phi_b[PI*32 + c0u + o]);
        const long  g  = ((long)(b*32 + c))*64 + i;
        const float fr = (FIRST ? f[g] : f_rest[g]) - hn;
        sq = fmaf(fr, fr, sq);
        if constexpr (!LAST) {
            f_rest[g] = fr;
            constexpr int cs = 64 / NPN;   // pool chunk for next stage
            float v = fr;
            if constexpr (cs > 1) {
#pragma unroll
                for (int off = cs >> 1; off > 0; off >>= 1) v += __shfl_xor(v, off);
            }
            if ((i & (cs - 1)) == 0)
                rest_next[((long)(b*NPN) + i/cs)*32 + c] = v * (1.0f/(float)cs);
        } else {
            f_hat_out[g] = f[g] - fr;      // f_hat = f - f_rest
        }
    }
#pragma unroll
    for (int off = 32; off > 0; off >>= 1) sq += __shfl_xor(sq, off);
    if ((t & 63) == 0) wsum[wv] = sq;
    __syncthreads();
    if (t == 0)
        atomicAdd(loss_acc, ((wsum[0]+wsum[1])+(wsum[2]+wsum[3])) * (1.25f/(7.0f*1048576.0f)));
}

extern "C" void kernel_launch(void* const* d_in, const int* in_sizes, int n_in,
                              void* d_out, int out_size, void* d_ws, size_t ws_size,
                              hipStream_t stream) {
    const float* f     = (const float*)d_in[0];
    const float* emb   = (const float*)d_in[1];
    const float* phi_w = (const float*)d_in[2];
    const float* phi_b = (const float*)d_in[3];
    float* out = (float*)d_out;
    float* ws  = (float*)d_ws;

    // ws layout (float offsets), total 2646016 floats ~= 10.6 MB (< round-4's proven 11.6 MB)
    float*  f_rest = ws;                          // 1048576
    float*  rest   = ws + 1048576;                // 1048576
    float*  esqf   = ws + 2097152;                // 4096
    double* esqd   = (double*)(ws + 2101248);     // 4096 doubles (8B-aligned)
    float*  wmidc  = ws + 2109440;                // 12288
    int*    minip  = (int*)(ws + 2121728);        // up to 524288 ints
    float*  loss_acc = out + TOT;

    vq_init<<<85, 256, 0, stream>>>(f, emb, phi_w, esqf, esqd, wmidc, rest, loss_acc);

    // pn = 1,2,4,8,16,32,64 ; pi = 0,0,1,2,2,3,3 ; big stages sized to 1024 blocks
#define SEARCH(PN, VS) vq_search<PN, VS><<<dim3((B_*PN)/512, VS), 256, 0, stream>>>( \
        rest, emb, esqf, esqd, minip)
#define FINAL(PN, VS, PI, NPN, FIRST, LAST) \
    vq_finalize<PN, VS, PI, NPN, FIRST, LAST><<<B_, 256, 0, stream>>>( \
        f, emb, rest, minip, esqd, wmidc, phi_b, f_rest, rest, loss_acc, out)

    SEARCH(1, 128);  FINAL(1, 128, 0, 2,  true,  false);
    SEARCH(2, 128);  FINAL(2, 128, 0, 4,  false, false);
    SEARCH(4, 128);  FINAL(4, 128, 1, 8,  false, false);
    SEARCH(8, 128);  FINAL(8, 128, 2, 16, false, false);
    SEARCH(16, 64);  FINAL(16, 64, 2, 32, false, false);
    SEARCH(32, 32);  FINAL(32, 32, 3, 64, false, false);
    SEARCH(64, 16);  FINAL(64, 16, 3, 64, false, true);
#undef SEARCH
#undef FINAL
}

// Round 6
// 680.056 us; speedup vs baseline: 2.1924x; 2.1924x over previous
//
#include <hip/hip_runtime.h>
#include <hip/hip_bf16.h>

// VectorQuantizer2 forward (VAR multi-scale VQ) on MI355X.
// B=512, C=32, H=64, W=1, V=4096 codes, scales pn=1,2,4,8,16,32,64.
// Identities: f_hat + f_rest == f  ->  loss_si = 1.25*mean(f_rest^2), out = f - f_rest_final.
// Conv 3x3 with W=1 + zero pad == 3x1 conv along H with kernel column kw=1.
// phi index per stage (exact fp64 replay of np.linspace ticks): si=0..6 -> pi=0,0,1,2,2,3,3.
// Argmin exactness (HW-validated r5): fp32 top-3 per chunk -> fp64 resolve of 3 candidates
// -> (double,int) partial; finalize reduces partials lexicographically -> exact argmin.
// r5 lesson: NO launch_bounds min-wave clause (VGPR cap 64 -> 363MB scratch spill traffic).
// r6: codes staged in LDS tiles (broadcast ds_read) to fix round-4's 36% VALUBusy stall.

#define B_ 512
#define C_ 32
#define H_ 64
#define V_ 4096
#define TOT (B_*C_*H_)   // 1048576

__device__ __forceinline__ float cubicw(float d) {
    d = fabsf(d);
    const float d2 = d * d, d3 = d2 * d;
    if (d <= 1.0f) return 1.25f * d3 - 2.25f * d2 + 1.0f;          // a=-0.75
    if (d < 2.0f)  return -0.75f * d3 + 3.75f * d2 - 6.0f * d + 3.0f;
    return 0.0f;
}

// fp64 dot of a row (8 float4 in regs) with a code row. Same accumulation order at every
// call site -> bit-identical scores -> exact cross-chunk comparisons.
__device__ __forceinline__ double dot64v(const float4* a, const float4* ef) {
    double s = 0.0;
#pragma unroll
    for (int k = 0; k < 8; ++k) {
        const float4 e = ef[k];
        s += (double)a[k].x * (double)e.x;
        s += (double)a[k].y * (double)e.y;
        s += (double)a[k].z * (double)e.z;
        s += (double)a[k].w * (double)e.w;
    }
    return s;
}

// ---------------- init: e_sq (f32+f64), compact conv weights, stage-0 pooled rest, zero loss
__global__ __launch_bounds__(256) void vq_init(
    const float* __restrict__ f, const float* __restrict__ emb,
    const float* __restrict__ phi_w,
    float* __restrict__ esqf, double* __restrict__ esqd,
    float* __restrict__ wmidc, float* __restrict__ rest0, float* __restrict__ loss_acc)
{
    const int blk = blockIdx.x, t = threadIdx.x;
    if (blk < 16) {                       // e_sq[4096] in fp64 (exact ordering source)
        const int v = blk * 256 + t;
        const float* er = emb + (long)v * 32;
        double s = 0.0;
#pragma unroll
        for (int k = 0; k < 32; ++k) { const double e = (double)er[k]; s += e * e; }
        esqd[v] = s;
        esqf[v] = (float)s;
    } else if (blk < 20) {                // wmidc[pi][c][cp][kh] = phi_w[pi][c][cp][kh][1]
        const int pi = blk - 16;
        for (int e = t; e < 3072; e += 256) {
            const int c = e / 96, r = e % 96, cp = r / 3, kh = r % 3;
            wmidc[pi * 3072 + e] = phi_w[(long)((pi*32 + c)*32 + cp)*9 + kh*3 + 1];
        }
    } else if (blk < 84) {                // rest0[b][c] = mean_i f[b][c][i]
        const int out = (blk - 20) * 256 + t;
        const int b = out >> 5, c = out & 31;
        const float4* fv = reinterpret_cast<const float4*>(f) + (long)(b*32 + c) * 16;
        float s0=0.f,s1=0.f,s2=0.f,s3=0.f;
#pragma unroll
        for (int k = 0; k < 16; ++k) {
            float4 e = fv[k];
            if ((k&3)==0){s0=s0+e.x+e.y+e.z+e.w;}
            else if((k&3)==1){s1=s1+e.x+e.y+e.z+e.w;}
            else if((k&3)==2){s2=s2+e.x+e.y+e.z+e.w;}
            else {s3=s3+e.x+e.y+e.z+e.w;}
        }
        rest0[out] = ((s0 + s1) + (s2 + s3)) * (1.0f / 64.0f);
    } else {
        if (t == 0) *loss_acc = 0.0f;
    }
}

// ---------------- VQ nearest-code search. 512 rows/block (2/thread); codes split VSPLIT
// ways; each chunk processed in LDS tiles of <=128 codes (broadcast ds_read_b128).
template<int PN, int VSPLIT>
__global__ __launch_bounds__(256) void vq_search(
    const float* __restrict__ rest,   // [B*PN][32]
    const float* __restrict__ emb,    // [4096][32]
    const float* __restrict__ esqf,   // [4096]
    const double* __restrict__ esqd,  // [4096]
    double* __restrict__ minv_p,      // [B*PN*VSPLIT] exact chunk-winner fp64 score
    int*    __restrict__ mini_p)      // [B*PN*VSPLIT] its index
{
    constexpr int VC = V_ / VSPLIT;           // codes per chunk
    constexpr int TILE = (VC < 128) ? VC : 128;
    constexpr int NT = VC / TILE;
    __shared__ __align__(16) float cds[TILE][32];
    __shared__ float ces[TILE];
    const int t = threadIdx.x;
    const long rowbase = (long)blockIdx.x * 512;
    const int vs = blockIdx.y;
    const long r0 = rowbase + t, r1 = r0 + 256;
    const float4* __restrict__ rv = reinterpret_cast<const float4*>(rest);
    const float4* __restrict__ ev = reinterpret_cast<const float4*>(emb);

    float4 a[8], b8[8];
#pragma unroll
    for (int k = 0; k < 8; ++k) { a[k] = rv[r0*8 + k]; b8[k] = rv[r1*8 + k]; }

    const int j0 = vs * VC;
    const float INF = 3.402823466e38f;
    float m1a=INF,m2a=INF,m3a=INF, m1b=INF,m2b=INF,m3b=INF;
    int i1a=j0,i2a=j0,i3a=j0, i1b=j0,i2b=j0,i3b=j0;

#pragma unroll 1
    for (int tt = 0; tt < NT; ++tt) {
        const int jt0 = j0 + tt * TILE;
        __syncthreads();                              // protect LDS before overwrite
        for (int e = t; e < TILE*8; e += 256)         // stage TILE codes -> LDS
            reinterpret_cast<float4*>(&cds[0][0])[e] = ev[(long)jt0*8 + e];
        if (t < TILE) ces[t] = esqf[jt0 + t];
        __syncthreads();

#pragma unroll 2
        for (int jj = 0; jj < TILE; ++jj) {
            const int j = jt0 + jj;
            const float4* __restrict__ ep = reinterpret_cast<const float4*>(cds[jj]);
            float4 e[8];
#pragma unroll
            for (int k = 0; k < 8; ++k) e[k] = ep[k];   // ds_read_b128, broadcast
            const float es = ces[jj];
            float pa[4]={0,0,0,0}, pb[4]={0,0,0,0};
#pragma unroll
            for (int k = 0; k < 8; ++k) {
                const int s_ = k & 3;
                pa[s_]=fmaf(a[k].x,e[k].x,pa[s_]); pa[s_]=fmaf(a[k].y,e[k].y,pa[s_]);
                pa[s_]=fmaf(a[k].z,e[k].z,pa[s_]); pa[s_]=fmaf(a[k].w,e[k].w,pa[s_]);
                pb[s_]=fmaf(b8[k].x,e[k].x,pb[s_]); pb[s_]=fmaf(b8[k].y,e[k].y,pb[s_]);
                pb[s_]=fmaf(b8[k].z,e[k].z,pb[s_]); pb[s_]=fmaf(b8[k].w,e[k].w,pb[s_]);
            }
            const float sa = fmaf(-2.0f,(pa[0]+pa[1])+(pa[2]+pa[3]),es);  // ||e||^2-2r.e
            const float sb = fmaf(-2.0f,(pb[0]+pb[1])+(pb[2]+pb[3]),es);
            { const bool c1=sa<m1a, c2=sa<m2a, c3=sa<m3a;
              m3a = c2?m2a:(c3?sa:m3a); i3a = c2?i2a:(c3?j:i3a);
              m2a = c1?m1a:(c2?sa:m2a); i2a = c1?i1a:(c2?j:i2a);
              m1a = c1?sa:m1a;          i1a = c1?j:i1a; }
            { const bool c1=sb<m1b, c2=sb<m2b, c3=sb<m3b;
              m3b = c2?m2b:(c3?sb:m3b); i3b = c2?i2b:(c3?j:i3b);
              m2b = c1?m1b:(c2?sb:m2b); i2b = c1?i1b:(c2?j:i2b);
              m1b = c1?sb:m1b;          i1b = c1?j:i1b; }
        }
    }

    // Exact fp64 resolve among the 3 fp32 candidates (lexicographic (value, index)).
    {
        double bv = 1e300; int bi = 0x7fffffff;
        const int cand[3] = { i1a, i2a, i3a };
#pragma unroll
        for (int c = 0; c < 3; ++c) {
            const int j = cand[c];
            const double v = esqd[j] - 2.0 * dot64v(a, ev + (long)j*8);
            if (v < bv || (v == bv && j < bi)) { bv = v; bi = j; }
        }
        minv_p[r0*VSPLIT + vs] = bv; mini_p[r0*VSPLIT + vs] = bi;
    }
    {
        double bv = 1e300; int bi = 0x7fffffff;
        const int cand[3] = { i1b, i2b, i3b };
#pragma unroll
        for (int c = 0; c < 3; ++c) {
            const int j = cand[c];
            const double v = esqd[j] - 2.0 * dot64v(b8, ev + (long)j*8);
            if (v < bv || (v == bv && j < bi)) { bv = v; bi = j; }
        }
        minv_p[r1*VSPLIT + vs] = bv; mini_p[r1*VSPLIT + vs] = bi;
    }
}

// ---------------- finalize: reduce partial argmins, gather, bicubic up, 3x1 conv,
//                  residual + loss + next-stage pooling
template<int PN, int VS, int PI, int NPN, bool FIRST, bool LAST>
__global__ __launch_bounds__(256) void vq_finalize(
    const float* __restrict__ f,
    const float* __restrict__ emb,
    const double* __restrict__ minv_p,   // [B*PN*VS]
    const int*   __restrict__ mini_p,
    const float* __restrict__ wmidc,     // [4][32][32][3]
    const float* __restrict__ phi_b,     // [4][32]
    float* __restrict__ f_rest,
    float* __restrict__ rest_next,       // [B*NPN][32]
    float* __restrict__ loss_acc,
    float* __restrict__ f_hat_out)
{
    __shared__ int   idx_s[PN];
    __shared__ float hs[32][65];
    __shared__ float huc[32][68];      // rows i+1 for i in [-1,64]; cols 0 and 65 zero pad
    __shared__ float wsum[4];
    const int t = threadIdx.x;
    const int b = blockIdx.x;

    // exact cross-chunk argmin: TPR threads per row, lexicographic (value, index) min.
    {
        constexpr int TPR = (256/PN < 8) ? (256/PN) : 8;   // 8,...,8,4
        constexpr int EPT = VS / TPR;
        static_assert(VS % TPR == 0, "VS % TPR");
        const int row = t / TPR, k = t % TPR;
        if (row < PN) {
            const long pbase = ((long)b*PN + row)*VS;
            double bv = 1e300; int bi = 0x7fffffff;
            for (int e = k*EPT; e < (k+1)*EPT; ++e) {
                const double v = minv_p[pbase + e];
                const int   ii = mini_p[pbase + e];
                if (v < bv || (v == bv && ii < bi)) { bv = v; bi = ii; }
            }
#pragma unroll
            for (int off = TPR>>1; off; off >>= 1) {
                const double ov = __shfl_xor(bv, off);
                const int    oi = __shfl_xor(bi, off);
                if (ov < bv || (ov == bv && oi < bi)) { bv = ov; bi = oi; }
            }
            if (k == 0) idx_s[row] = bi;
        }
    }
    if (t < 32) { huc[t][0] = 0.0f; huc[t][65] = 0.0f; }
    __syncthreads();

    for (int e = t; e < PN*32; e += 256) {   // gather codes: hs[c][p]
        const int c = e & 31, p = e >> 5;
        hs[c][p] = emb[(long)idx_s[p]*32 + c];
    }
    __syncthreads();

    const int i  = t & 63;             // lane = output position along H
    const int wv = t >> 6;             // wave = channel block of 8
    const int c0 = wv * 8;
    if constexpr (PN == 64) {
#pragma unroll
        for (int o = 0; o < 8; ++o) huc[c0+o][i+1] = hs[c0+o][i];
    } else {
        constexpr float scale = (float)PN / 64.0f;
        const float src = ((float)i + 0.5f) * scale - 0.5f;
        const float fi0 = floorf(src);
        const float tt  = src - fi0;
        const int   i0  = (int)fi0;
        const float w0 = cubicw(tt + 1.0f), w1 = cubicw(tt);
        const float w2 = cubicw(1.0f - tt), w3 = cubicw(2.0f - tt);
        const int k0 = min(max(i0 - 1, 0), PN - 1);
        const int k1 = min(max(i0    , 0), PN - 1);
        const int k2 = min(max(i0 + 1, 0), PN - 1);
        const int k3 = min(max(i0 + 2, 0), PN - 1);
#pragma unroll
        for (int o = 0; o < 8; ++o) {
            const int c = c0 + o;
            float v = w0 * hs[c][k0];
            v = fmaf(w1, hs[c][k1], v);
            v = fmaf(w2, hs[c][k2], v);
            v = fmaf(w3, hs[c][k3], v);
            huc[c][i+1] = v;
        }
    }
    __syncthreads();

    // 3x1 conv along H; weights wave-uniform -> scalar loads
    const int c0u = __builtin_amdgcn_readfirstlane(c0);
    const float* __restrict__ wb = wmidc + PI*3072 + c0u*96;
    float acc[8] = {0,0,0,0,0,0,0,0};
#pragma unroll 8
    for (int cp = 0; cp < 32; ++cp) {
        const float x0 = huc[cp][i];
        const float x1 = huc[cp][i+1];
        const float x2 = huc[cp][i+2];
#pragma unroll
        for (int o = 0; o < 8; ++o) {
            const float* w = wb + o*96 + cp*3;
            acc[o] = fmaf(w[0], x0, acc[o]);
            acc[o] = fmaf(w[1], x1, acc[o]);
            acc[o] = fmaf(w[2], x2, acc[o]);
        }
    }

    float sq = 0.0f;
#pragma unroll
    for (int o = 0; o < 8; ++o) {
        const int c = c0 + o;
        const float h  = huc[c][i+1];
        const float hn = 0.5f * h + 0.5f * (acc[o] + phi_b[PI*32 + c0u + o]);
        const long  g  = ((long)(b*32 + c))*64 + i;
        const float fr = (FIRST ? f[g] : f_rest[g]) - hn;
        sq = fmaf(fr, fr, sq);
        if constexpr (!LAST) {
            f_rest[g] = fr;
            constexpr int cs = 64 / NPN;   // pool chunk for next stage
            float v = fr;
            if constexpr (cs > 1) {
#pragma unroll
                for (int off = cs >> 1; off > 0; off >>= 1) v += __shfl_xor(v, off);
            }
            if ((i & (cs - 1)) == 0)
                rest_next[((long)(b*NPN) + i/cs)*32 + c] = v * (1.0f/(float)cs);
        } else {
            f_hat_out[g] = f[g] - fr;      // f_hat = f - f_rest
        }
    }
#pragma unroll
    for (int off = 32; off > 0; off >>= 1) sq += __shfl_xor(sq, off);
    if ((t & 63) == 0) wsum[wv] = sq;
    __syncthreads();
    if (t == 0)
        atomicAdd(loss_acc, ((wsum[0]+wsum[1])+(wsum[2]+wsum[3])) * (1.25f/(7.0f*1048576.0f)));
}

extern "C" void kernel_launch(void* const* d_in, const int* in_sizes, int n_in,
                              void* d_out, int out_size, void* d_ws, size_t ws_size,
                              hipStream_t stream) {
    const float* f     = (const float*)d_in[0];
    const float* emb   = (const float*)d_in[1];
    const float* phi_w = (const float*)d_in[2];
    const float* phi_b = (const float*)d_in[3];
    float* out = (float*)d_out;
    float* ws  = (float*)d_ws;

    // ws layout (float offsets), total 2908160 floats = 11.63 MB (proven in round 4)
    float*  f_rest = ws;                          // 1048576
    float*  rest   = ws + 1048576;                // 1048576
    float*  esqf   = ws + 2097152;                // 4096
    double* esqd   = (double*)(ws + 2101248);     // 4096 doubles
    float*  wmidc  = ws + 2109440;                // 12288
    double* minvd  = (double*)(ws + 2121728);     // 262144 doubles
    int*    minip  = (int*)(ws + 2646016);        // 262144 ints
    float*  loss_acc = out + TOT;

    vq_init<<<85, 256, 0, stream>>>(f, emb, phi_w, esqf, esqd, wmidc, rest, loss_acc);

    // pn = 1,2,4,8,16,32,64 ; pi = 0,0,1,2,2,3,3 ; rows*VS <= 262144 every stage
#define SEARCH(PN, VS) vq_search<PN, VS><<<dim3((B_*PN)/512, VS), 256, 0, stream>>>( \
        rest, emb, esqf, esqd, minvd, minip)
#define FINAL(PN, VS, PI, NPN, FIRST, LAST) \
    vq_finalize<PN, VS, PI, NPN, FIRST, LAST><<<B_, 256, 0, stream>>>( \
        f, emb, minvd, minip, wmidc, phi_b, f_rest, rest, loss_acc, out)

    SEARCH(1, 128);  FINAL(1, 128, 0, 2,  true,  false);
    SEARCH(2, 128);  FINAL(2, 128, 0, 4,  false, false);
    SEARCH(4, 64);   FINAL(4, 64, 1, 8,  false, false);
    SEARCH(8, 64);   FINAL(8, 64, 2, 16, false, false);
    SEARCH(16, 32);  FINAL(16, 32, 2, 32, false, false);
    SEARCH(32, 16);  FINAL(32, 16, 3, 64, false, false);
    SEARCH(64, 8);   FINAL(64, 8, 3, 64, false, true);
#undef SEARCH
#undef FINAL
}

// Round 8
// 579.388 us; speedup vs baseline: 2.5733x; 1.1737x over previous
//
#include <hip/hip_runtime.h>
#include <hip/hip_bf16.h>

// VectorQuantizer2 forward (VAR multi-scale VQ) on MI355X.
// B=512, C=32, H=64, W=1, V=4096 codes, scales pn=1,2,4,8,16,32,64.
// f_hat + f_rest == f -> loss_si = 1.25*mean(f_rest^2); out = f - f_rest_final.
// Conv3x3 with W=1 == 3x1 conv along H (kernel column kw=1). pi = 0,0,1,2,2,3,3.
// r8: scoring on the MATRIX pipe: score = ||e||^2 - 2*r.e via mfma_f32_16x16x32_bf16
// with FULL 2xbf16 split (ll+lh+hl+hh, smallest-first: representation exact to 2^-18,
// residual error = fp32-accum class, same envelope as the r4/r6-validated scalar path).
// Per-lane top-3 over its col-slice -> lex butterfly merge -> exact fp32 top-3 per
// (row,chunk) -> fp64 resolve of 3 cands -> (double,int) partial; finalize lex-reduces
// partials (r6-validated). LDS staged [kg][TILE] so staging writes are consecutive-slot
// (r6 PMC: 0 conflicts). No launch_bounds waves clause (r5 spill lesson).

#define B_ 512
#define C_ 32
#define H_ 64
#define V_ 4096
#define TOT (B_*C_*H_)   // 1048576

typedef __attribute__((ext_vector_type(8))) short bf16x8;
typedef __attribute__((ext_vector_type(4))) float f32x4;

__device__ __forceinline__ ushort f2bf(float f) {          // RNE float->bf16 bits
    unsigned u = __float_as_uint(f);
    return (ushort)((u + 0x7fffu + ((u >> 16) & 1u)) >> 16);
}
__device__ __forceinline__ float bf2f(ushort h) { return __uint_as_float(((unsigned)h) << 16); }

__device__ __forceinline__ float cubicw(float d) {
    d = fabsf(d);
    const float d2 = d * d, d3 = d2 * d;
    if (d <= 1.0f) return 1.25f * d3 - 2.25f * d2 + 1.0f;          // a=-0.75
    if (d < 2.0f)  return -0.75f * d3 + 3.75f * d2 - 6.0f * d + 3.0f;
    return 0.0f;
}

// fp64 dot; SAME accumulation order at every call site -> bit-identical scores.
__device__ __forceinline__ double dot64v(const float4* a, const float4* ef) {
    double s = 0.0;
#pragma unroll
    for (int k = 0; k < 8; ++k) {
        const float4 e = ef[k];
        s += (double)a[k].x * (double)e.x;
        s += (double)a[k].y * (double)e.y;
        s += (double)a[k].z * (double)e.z;
        s += (double)a[k].w * (double)e.w;
    }
    return s;
}

// ---------------- init: esq f32/f64, emb bf16 hi/lo, conv weights, stage-0 rest(+hi/lo)
__global__ __launch_bounds__(256) void vq_init(
    const float* __restrict__ f, const float* __restrict__ emb,
    const float* __restrict__ phi_w,
    float* __restrict__ esqf, double* __restrict__ esqd,
    ushort* __restrict__ emb_hi, ushort* __restrict__ emb_lo,
    float* __restrict__ wmidc, float* __restrict__ rest0,
    ushort* __restrict__ r0_hi, ushort* __restrict__ r0_lo,
    float* __restrict__ loss_acc)
{
    const int blk = blockIdx.x, t = threadIdx.x;
    if (blk < 16) {                       // esq + emb hi/lo split
        const int v = blk * 256 + t;
        const float* er = emb + (size_t)v * 32;
        double s = 0.0;
#pragma unroll
        for (int k = 0; k < 32; ++k) {
            const float ef = er[k];
            const double e = (double)ef; s += e * e;
            const ushort hh = f2bf(ef);
            emb_hi[(size_t)v*32 + k] = hh;
            emb_lo[(size_t)v*32 + k] = f2bf(ef - bf2f(hh));
        }
        esqd[v] = s; esqf[v] = (float)s;
    } else if (blk < 20) {                // wmidc[pi][c][cp][kh] = phi_w[...][kh][1]
        const int pi = blk - 16;
        for (int e = t; e < 3072; e += 256) {
            const int c = e / 96, r = e % 96, cp = r / 3, kh = r % 3;
            wmidc[pi * 3072 + e] = phi_w[(size_t)((pi*32 + c)*32 + cp)*9 + kh*3 + 1];
        }
    } else if (blk < 84) {                // rest0[b][c] = mean_i f[b][c][i]  (+hi/lo)
        const int out = (blk - 20) * 256 + t;
        const float4* fv = reinterpret_cast<const float4*>(f) + (size_t)out * 16;
        float s0=0.f,s1=0.f,s2=0.f,s3=0.f;
#pragma unroll
        for (int k = 0; k < 16; ++k) {
            float4 e = fv[k];
            if ((k&3)==0){s0=s0+e.x+e.y+e.z+e.w;}
            else if((k&3)==1){s1=s1+e.x+e.y+e.z+e.w;}
            else if((k&3)==2){s2=s2+e.x+e.y+e.z+e.w;}
            else {s3=s3+e.x+e.y+e.z+e.w;}
        }
        const float val = ((s0 + s1) + (s2 + s3)) * (1.0f / 64.0f);
        rest0[out] = val;
        const ushort hh = f2bf(val);
        r0_hi[out] = hh; r0_lo[out] = f2bf(val - bf2f(hh));
    } else {
        if (t == 0) *loss_acc = 0.0f;
    }
}

// ---------------- MFMA VQ search: block = 128 rows (4 waves x 32), chunk = VC codes.
template<int VSPLIT>
__global__ __launch_bounds__(256) void vq_search_mfma(
    const float*  __restrict__ restf,    // [R][32] f32 (fp64 resolve)
    const ushort* __restrict__ rest_hi,  // [R][32] bf16 hi
    const ushort* __restrict__ rest_lo,
    const ushort* __restrict__ emb_hi,   // [4096][32]
    const ushort* __restrict__ emb_lo,
    const float*  __restrict__ embf,     // [4096][32] f32 (fp64 resolve)
    const float*  __restrict__ esqf,
    const double* __restrict__ esqd,
    double* __restrict__ minv_p,         // [R*VSPLIT]
    int*    __restrict__ mini_p)
{
    constexpr int VC = V_ / VSPLIT;
    constexpr int TILE = (VC < 128) ? VC : 128;
    static_assert(TILE % 16 == 0, "tile");
    __shared__ float4 bsh4[2][TILE * 4];     // [kg][TILE] slots of 16B (8 bf16)
    __shared__ float essh[TILE];
    const int t = threadIdx.x;
    const int wave = t >> 6, lane = t & 63;
    const int col = lane & 15, g = lane >> 4;
    const int rb = blockIdx.x * 128 + wave * 32;
    const int vs = blockIdx.y, j0 = vs * VC;

    // A fragments (row = lane%16, k = 8*(lane/16)+i : contiguous 16B)
    const int ko = g * 8;
    const bf16x8 ah0 = *(const bf16x8*)(rest_hi + (size_t)(rb + col) * 32 + ko);
    const bf16x8 al0 = *(const bf16x8*)(rest_lo + (size_t)(rb + col) * 32 + ko);
    const bf16x8 ah1 = *(const bf16x8*)(rest_hi + (size_t)(rb + 16 + col) * 32 + ko);
    const bf16x8 al1 = *(const bf16x8*)(rest_lo + (size_t)(rb + 16 + col) * 32 + ko);

    const float INF = 3.402823466e38f;
    float m[2][4][3]; int id[2][4][3];
#pragma unroll
    for (int rt = 0; rt < 2; ++rt)
#pragma unroll
        for (int r = 0; r < 4; ++r)
#pragma unroll
            for (int k = 0; k < 3; ++k) { m[rt][r][k] = INF; id[rt][r][k] = j0; }

#define INSERT(RT, R, SV, JC) do {                                             \
        const float _s = (SV);                                                 \
        const bool c1 = _s < m[RT][R][0];                                      \
        const bool c2 = _s < m[RT][R][1];                                      \
        const bool c3 = _s < m[RT][R][2];                                      \
        m[RT][R][2]  = c2 ? m[RT][R][1]  : (c3 ? _s  : m[RT][R][2]);           \
        id[RT][R][2] = c2 ? id[RT][R][1] : (c3 ? (JC) : id[RT][R][2]);         \
        m[RT][R][1]  = c1 ? m[RT][R][0]  : (c2 ? _s  : m[RT][R][1]);           \
        id[RT][R][1] = c1 ? id[RT][R][0] : (c2 ? (JC) : id[RT][R][1]);         \
        m[RT][R][0]  = c1 ? _s  : m[RT][R][0];                                 \
        id[RT][R][0] = c1 ? (JC) : id[RT][R][0];                               \
    } while (0)

#pragma unroll 1
    for (int tb = 0; tb < VC; tb += TILE) {
        __syncthreads();
        // stage TILE codes (hi+lo) -> LDS; cl-fast: consecutive lanes -> consecutive slots
        for (int e = t; e < TILE * 4; e += 256) {
            const int cl = e & (TILE - 1), kg = e / TILE;
            const size_t code = (size_t)(j0 + tb + cl);
            bsh4[0][kg * TILE + cl] = ((const float4*)(emb_hi + code * 32))[kg];
            bsh4[1][kg * TILE + cl] = ((const float4*)(emb_lo + code * 32))[kg];
        }
        for (int e = t; e < TILE; e += 256) essh[e] = esqf[j0 + tb + e];
        __syncthreads();
#pragma unroll 2
        for (int jt = 0; jt < TILE / 16; ++jt) {
            const int slot = g * TILE + jt * 16 + col;   // 16 consecutive 16B per group
            const bf16x8 bh = ((const bf16x8*)bsh4[0])[slot];
            const bf16x8 bl = ((const bf16x8*)bsh4[1])[slot];
            const float es = essh[jt * 16 + col];
            const int jc = j0 + tb + jt * 16;            // tile base code (uniform)
            // full split, smallest terms first: ll + lh + hl + hh
            f32x4 acc0 = {0.f, 0.f, 0.f, 0.f};
            acc0 = __builtin_amdgcn_mfma_f32_16x16x32_bf16(al0, bl, acc0, 0, 0, 0);
            acc0 = __builtin_amdgcn_mfma_f32_16x16x32_bf16(al0, bh, acc0, 0, 0, 0);
            acc0 = __builtin_amdgcn_mfma_f32_16x16x32_bf16(ah0, bl, acc0, 0, 0, 0);
            acc0 = __builtin_amdgcn_mfma_f32_16x16x32_bf16(ah0, bh, acc0, 0, 0, 0);
            f32x4 acc1 = {0.f, 0.f, 0.f, 0.f};
            acc1 = __builtin_amdgcn_mfma_f32_16x16x32_bf16(al1, bl, acc1, 0, 0, 0);
            acc1 = __builtin_amdgcn_mfma_f32_16x16x32_bf16(al1, bh, acc1, 0, 0, 0);
            acc1 = __builtin_amdgcn_mfma_f32_16x16x32_bf16(ah1, bl, acc1, 0, 0, 0);
            acc1 = __builtin_amdgcn_mfma_f32_16x16x32_bf16(ah1, bh, acc1, 0, 0, 0);
#pragma unroll
            for (int r = 0; r < 4; ++r) {
                { const float s = fmaf(-2.0f, acc0[r], es); INSERT(0, r, s, jc); }
                { const float s = fmaf(-2.0f, acc1[r], es); INSERT(1, r, s, jc); }
            }
        }
    }
#undef INSERT

    // idx base -> full code id (add own col) before cross-lane merge
#pragma unroll
    for (int rt = 0; rt < 2; ++rt)
#pragma unroll
        for (int r = 0; r < 4; ++r)
#pragma unroll
            for (int k = 0; k < 3; ++k) id[rt][r][k] += col;

    // butterfly lex-merge across the 16 cols of each lane group
#define MINSERT(RT, R, VB, IB) do {                                            \
        const float _vb = (VB); const int _ib = (IB);                          \
        const bool l1 = (_vb < m[RT][R][0]) || (_vb == m[RT][R][0] && _ib < id[RT][R][0]); \
        const bool l2 = (_vb < m[RT][R][1]) || (_vb == m[RT][R][1] && _ib < id[RT][R][1]); \
        const bool l3 = (_vb < m[RT][R][2]) || (_vb == m[RT][R][2] && _ib < id[RT][R][2]); \
        m[RT][R][2]  = l2 ? m[RT][R][1]  : (l3 ? _vb : m[RT][R][2]);           \
        id[RT][R][2] = l2 ? id[RT][R][1] : (l3 ? _ib : id[RT][R][2]);          \
        m[RT][R][1]  = l1 ? m[RT][R][0]  : (l2 ? _vb : m[RT][R][1]);           \
        id[RT][R][1] = l1 ? id[RT][R][0] : (l2 ? _ib : id[RT][R][1]);          \
        m[RT][R][0]  = l1 ? _vb : m[RT][R][0];                                 \
        id[RT][R][0] = l1 ? _ib : id[RT][R][0];                                \
    } while (0)
#pragma unroll
    for (int off = 1; off <= 8; off <<= 1) {
#pragma unroll
        for (int rt = 0; rt < 2; ++rt)
#pragma unroll
            for (int r = 0; r < 4; ++r) {
                float vb0 = __shfl_xor(m[rt][r][0], off);
                float vb1 = __shfl_xor(m[rt][r][1], off);
                float vb2 = __shfl_xor(m[rt][r][2], off);
                int   ib0 = __shfl_xor(id[rt][r][0], off);
                int   ib1 = __shfl_xor(id[rt][r][1], off);
                int   ib2 = __shfl_xor(id[rt][r][2], off);
                MINSERT(rt, r, vb0, ib0);
                MINSERT(rt, r, vb1, ib1);
                MINSERT(rt, r, vb2, ib2);
            }
    }
#undef MINSERT

    // fp64 resolve: 12 lanes/group each score one (row_local, cand) pair
    const int base = lane & ~15;
    const int rl = col / 3;
    const int ck = col - rl * 3;
    const bool act = (col < 12);
#pragma unroll
    for (int rt = 0; rt < 2; ++rt) {
        int cand = j0;
#pragma unroll
        for (int r = 0; r < 4; ++r)
#pragma unroll
            for (int k = 0; k < 3; ++k)
                cand = (col == r * 3 + k) ? id[rt][r][k] : cand;
        const int rowg = rb + rt * 16 + g * 4 + (act ? rl : 0);
        const int candL = act ? cand : 0;
        float4 a4[8];
        const float4* rr = (const float4*)(restf + (size_t)rowg * 32);
#pragma unroll
        for (int k = 0; k < 8; ++k) a4[k] = rr[k];
        double v = esqd[candL] - 2.0 * dot64v(a4, (const float4*)(embf + (size_t)candL * 32));
        if (!act) v = 1e300;
        const int sl = base + (act ? rl : 0) * 3;
        const double v0 = __shfl(v, sl + 0); const int i0 = __shfl(candL, sl + 0);
        const double v1 = __shfl(v, sl + 1); const int i1 = __shfl(candL, sl + 1);
        const double v2 = __shfl(v, sl + 2); const int i2 = __shfl(candL, sl + 2);
        double bv = v0; int bi = i0;
        if (v1 < bv || (v1 == bv && i1 < bi)) { bv = v1; bi = i1; }
        if (v2 < bv || (v2 == bv && i2 < bi)) { bv = v2; bi = i2; }
        if (act && ck == 0) {
            minv_p[(size_t)rowg * VSPLIT + vs] = bv;
            mini_p[(size_t)rowg * VSPLIT + vs] = bi;
        }
    }
}

// ---------------- finalize: reduce partials, gather, bicubic, 3x1 conv, residual+loss+pool.
// grid (B, 2): blockIdx.y = channel half (16 ch); 4 waves x 4 ch/thread.
template<int PN, int VS, int PI, int NPN, bool FIRST, bool LAST>
__global__ __launch_bounds__(256) void vq_finalize(
    const float* __restrict__ f,
    const float* __restrict__ emb,
    const double* __restrict__ minv_p,
    const int*   __restrict__ mini_p,
    const float* __restrict__ wmidc,
    const float* __restrict__ phi_b,
    float* __restrict__ f_rest,
    float* __restrict__ rest_next,
    ushort* __restrict__ rn_hi, ushort* __restrict__ rn_lo,
    float* __restrict__ loss_acc,
    float* __restrict__ f_hat_out)
{
    __shared__ int   idx_s[PN];
    __shared__ float hs[32][65];
    __shared__ float huc[32][68];
    __shared__ float wsum[4];
    const int t = threadIdx.x;
    const int b = blockIdx.x;
    const int half = blockIdx.y;

    {   // lex argmin over VS chunk winners
        constexpr int CAP = (256/PN < 8) ? (256/PN) : 8;
        constexpr int TPR = (VS < CAP) ? VS : CAP;
        constexpr int EPT = VS / TPR;
        static_assert(VS % TPR == 0, "VS%TPR");
        const int row = t / TPR, k = t % TPR;
        if (row < PN) {
            const size_t pbase = ((size_t)b*PN + row)*VS;
            double bv = 1e300; int bi = 0x7fffffff;
            for (int e = k*EPT; e < (k+1)*EPT; ++e) {
                const double v = minv_p[pbase + e];
                const int   ii = mini_p[pbase + e];
                if (v < bv || (v == bv && ii < bi)) { bv = v; bi = ii; }
            }
#pragma unroll
            for (int off = TPR>>1; off; off >>= 1) {
                const double ov = __shfl_xor(bv, off);
                const int    oi = __shfl_xor(bi, off);
                if (ov < bv || (ov == bv && oi < bi)) { bv = ov; bi = oi; }
            }
            if (k == 0) idx_s[row] = bi;
        }
    }
    if (t < 32) { huc[t][0] = 0.0f; huc[t][65] = 0.0f; }
    __syncthreads();

    for (int e = t; e < PN*32; e += 256) {   // gather codes: hs[c][p]
        const int c = e & 31, p = e >> 5;
        hs[c][p] = emb[(size_t)idx_s[p]*32 + c];
    }
    __syncthreads();

    const int i  = t & 63;
    const int wv = t >> 6;
    const int cb0 = wv * 8;                  // huc build covers all 32 channels
    if constexpr (PN == 64) {
#pragma unroll
        for (int o = 0; o < 8; ++o) huc[cb0+o][i+1] = hs[cb0+o][i];
    } else {
        constexpr float scale = (float)PN / 64.0f;
        const float src = ((float)i + 0.5f) * scale - 0.5f;
        const float fi0 = floorf(src);
        const float tt  = src - fi0;
        const int   i0  = (int)fi0;
        const float w0 = cubicw(tt + 1.0f), w1 = cubicw(tt);
        const float w2 = cubicw(1.0f - tt), w3 = cubicw(2.0f - tt);
        const int k0 = min(max(i0 - 1, 0), PN - 1);
        const int k1 = min(max(i0    , 0), PN - 1);
        const int k2 = min(max(i0 + 1, 0), PN - 1);
        const int k3 = min(max(i0 + 2, 0), PN - 1);
#pragma unroll
        for (int o = 0; o < 8; ++o) {
            const int c = cb0 + o;
            float v = w0 * hs[c][k0];
            v = fmaf(w1, hs[c][k1], v);
            v = fmaf(w2, hs[c][k2], v);
            v = fmaf(w3, hs[c][k3], v);
            huc[c][i+1] = v;
        }
    }
    __syncthreads();

    // 3x1 conv along H for this half's 4 channels/thread
    const int c0 = half*16 + wv*4;
    const int c0u = __builtin_amdgcn_readfirstlane(c0);
    const float* __restrict__ wb = wmidc + PI*3072 + c0u*96;
    float acc[4] = {0,0,0,0};
#pragma unroll 8
    for (int cp = 0; cp < 32; ++cp) {
        const float x0 = huc[cp][i];
        const float x1 = huc[cp][i+1];
        const float x2 = huc[cp][i+2];
#pragma unroll
        for (int o = 0; o < 4; ++o) {
            const float* w = wb + o*96 + cp*3;
            acc[o] = fmaf(w[0], x0, acc[o]);
            acc[o] = fmaf(w[1], x1, acc[o]);
            acc[o] = fmaf(w[2], x2, acc[o]);
        }
    }

    float sq = 0.0f;
#pragma unroll
    for (int o = 0; o < 4; ++o) {
        const int c = c0 + o;
        const float h  = huc[c][i+1];
        const float hn = 0.5f * h + 0.5f * (acc[o] + phi_b[PI*32 + c0u + o]);
        const size_t gg = ((size_t)(b*32 + c))*64 + i;
        const float fr = (FIRST ? f[gg] : f_rest[gg]) - hn;
        sq = fmaf(fr, fr, sq);
        if constexpr (!LAST) {
            f_rest[gg] = fr;
            constexpr int cs = 64 / NPN;
            float v = fr;
            if constexpr (cs > 1) {
#pragma unroll
                for (int off = cs >> 1; off > 0; off >>= 1) v += __shfl_xor(v, off);
            }
            if ((i & (cs - 1)) == 0) {
                const float pv = v * (1.0f/(float)cs);
                const size_t ridx = ((size_t)(b*NPN) + i/cs)*32 + c;
                rest_next[ridx] = pv;
                const ushort ph = f2bf(pv);
                rn_hi[ridx] = ph;
                rn_lo[ridx] = f2bf(pv - bf2f(ph));
            }
        } else {
            f_hat_out[gg] = f[gg] - fr;
        }
    }
#pragma unroll
    for (int off = 32; off > 0; off >>= 1) sq += __shfl_xor(sq, off);
    if ((t & 63) == 0) wsum[wv] = sq;
    __syncthreads();
    if (t == 0)
        atomicAdd(loss_acc, ((wsum[0]+wsum[1])+(wsum[2]+wsum[3])) * (1.25f/(7.0f*1048576.0f)));
}

extern "C" void kernel_launch(void* const* d_in, const int* in_sizes, int n_in,
                              void* d_out, int out_size, void* d_ws, size_t ws_size,
                              hipStream_t stream) {
    const float* f     = (const float*)d_in[0];
    const float* emb   = (const float*)d_in[1];
    const float* phi_w = (const float*)d_in[2];
    const float* phi_b = (const float*)d_in[3];
    float* out = (float*)d_out;
    float* ws  = (float*)d_ws;

    // ws layout (float offsets), total ~14.1 MB
    float*  f_rest  = ws;                           // 1048576 f
    float*  rest    = ws + 1048576;                 // 1048576 f
    double* esqd    = (double*)(ws + 2097152);      // 4096 d
    double* minvd   = (double*)(ws + 2105344);      // 131072 d
    float*  esqf    = ws + 2367488;                 // 4096 f
    float*  wmidc   = ws + 2371584;                 // 12288 f
    int*    minip   = (int*)(ws + 2383872);         // 131072 i
    ushort* rest_hi = (ushort*)(ws + 2514944);      // 1048576 us
    ushort* rest_lo = (ushort*)(ws + 3039232);      // 1048576 us
    ushort* emb_hi  = (ushort*)(ws + 3563520);      // 131072 us
    ushort* emb_lo  = (ushort*)(ws + 3629056);      // 131072 us
    float*  loss_acc = out + TOT;

    vq_init<<<85, 256, 0, stream>>>(f, emb, phi_w, esqf, esqd, emb_hi, emb_lo,
                                    wmidc, rest, rest_hi, rest_lo, loss_acc);

    // pn = 1,2,4,8,16,32,64 ; pi = 0,0,1,2,2,3,3 ; PN*VS = 256 -> partials 131072, 1024 blocks
#define SEARCH(PN, VS) vq_search_mfma<VS><<<dim3(4*PN, VS), 256, 0, stream>>>( \
        rest, rest_hi, rest_lo, emb_hi, emb_lo, emb, esqf, esqd, minvd, minip)
#define FINAL(PN, VS, PI, NPN, FIRST, LAST) \
    vq_finalize<PN, VS, PI, NPN, FIRST, LAST><<<dim3(B_, 2), 256, 0, stream>>>( \
        f, emb, minvd, minip, wmidc, phi_b, f_rest, rest, rest_hi, rest_lo, loss_acc, out)

    SEARCH(1, 256);  FINAL(1, 256, 0, 2,  true,  false);
    SEARCH(2, 128);  FINAL(2, 128, 0, 4,  false, false);
    SEARCH(4, 64);   FINAL(4, 64, 1, 8,  false, false);
    SEARCH(8, 32);   FINAL(8, 32, 2, 16, false, false);
    SEARCH(16, 16);  FINAL(16, 16, 2, 32, false, false);
    SEARCH(32, 8);   FINAL(32, 8, 3, 64, false, false);
    SEARCH(64, 4);   FINAL(64, 4, 3, 64, false, true);
#undef SEARCH
#undef FINAL
}